// Round 1
// 599.150 us; speedup vs baseline: 1.1364x; 1.1364x over previous
//
#include <hip/hip_runtime.h>

// Problem: B=4096, K=64, DIM=512, obj=0:
//   out = sum_{b, k != labels[b]} exp( -sum_d (inputs[b,d] - decoded[b,k,d])^2 )
//
// R2: exact early-exit (branch-and-bound on the fp32 underflow boundary).
//   expf(-x) == 0.0f exactly for x >= 104 (e^-104 < 2^-150, below half the
//   smallest subnormal). Partial sums of squares are monotone non-decreasing
//   in fp32 (a + b >= a for b >= 0, round-to-nearest). So if the squared
//   distance over dims [0,128) already reaches SKIP_T=128, the term is
//   exactly 0.0f and dims [128,512) of that decoded row need never be read.
//   This is bit-exact for ALL inputs: a rare fallback path finishes the full
//   row whenever the partial sum is below threshold.
//   On N(0,1) data, s_128 ~ 2*chi2_128 (mean 256, sigma 32):
//   P(s_128 < 128) ~ 5e-9  => ~0.001 expected fallbacks in the whole problem.
//   Traffic: 537 MB -> ~138 MB (first 512B of each 2KiB row).
//
// Load layout: one wave instruction covers TWO rows' 512B prefixes
// (lanes 0-31 -> row k, lanes 32-63 -> row k+1; 16B/lane = 1KiB/instruction).
// Butterflies are 5-stage within each 32-lane half. expf only runs on the
// (almost never taken) survivor path.

#define B_SZ 4096
#define K_SZ 64
#define DIM  512
#define ROW_F4 (DIM / 4)   // 128 float4 per decoded row
#define SKIP_T 128.0f

template <typename LT>
__global__ __launch_bounds__(256) void score_kernel(
    const float* __restrict__ inputs,   // (B, DIM)
    const float* __restrict__ decoded,  // (B, K, DIM)
    const LT*    __restrict__ labels,   // (B,)
    float* __restrict__ partials)       // (B,) in workspace
{
    const int b    = blockIdx.x;
    const int tid  = threadIdx.x;
    const int wave = tid >> 6;   // 0..3
    const int lane = tid & 63;
    const int m    = lane & 31;  // lane within half-wave
    const int g    = lane >> 5;  // half-wave group 0/1

    // Half-wave covers dims [0,128): lane m holds inputs[b, 4m..4m+3].
    const float4* inp = (const float4*)(inputs + (size_t)b * DIM);
    const float4 in1 = inp[m];

    const int lab = (int)labels[b];
    const float4* dec = (const float4*)(decoded + (size_t)b * K_SZ * DIM);

    // Wave w owns k = 16w .. 16w+15. Iteration j: half g covers k = 16w+2j+g.
    const int kbase = wave * 16 + g;

    // Phase A: pure streaming over row prefixes — 8 independent dwordx4 loads.
    float s[8];
    #pragma unroll
    for (int j = 0; j < 8; ++j) {
        const float4 d = dec[(size_t)(kbase + 2 * j) * ROW_F4 + m];
        float dx, t;
        dx = in1.x - d.x; t  = dx * dx;
        dx = in1.y - d.y; t += dx * dx;
        dx = in1.z - d.z; t += dx * dx;
        dx = in1.w - d.w; t += dx * dx;
        s[j] = t;
    }

    // Phase B: 8 independent 5-stage butterflies (offsets 16..1 stay inside
    // each 32-lane half). Result is half-wave-uniform: s[j] = s_128 for its k.
    #pragma unroll
    for (int j = 0; j < 8; ++j) {
        float t = s[j];
        #pragma unroll
        for (int off = 16; off; off >>= 1)
            t += __shfl_xor(t, off, 64);
        s[j] = t;
    }

    // Phase C: threshold. s_128 >= SKIP_T  =>  exact 0.0f contribution.
    float acc = 0.0f;
    #pragma unroll
    for (int j = 0; j < 8; ++j) {
        const int k = kbase + 2 * j;
        float sv = s[j];
        if (__any(sv < SKIP_T)) {            // wave-uniform, ~never taken
            // Exact fallback: finish dims [128,512) for this j's two rows.
            const float4* rowt = dec + (size_t)k * ROW_F4;
            float t = 0.0f;
            #pragma unroll
            for (int c = 1; c < 4; ++c) {
                const float4 dv = rowt[c * 32 + m];
                const float4 iv = inp[c * 32 + m];
                float dx;
                dx = iv.x - dv.x; t += dx * dx;
                dx = iv.y - dv.y; t += dx * dx;
                dx = iv.z - dv.z; t += dx * dx;
                dx = iv.w - dv.w; t += dx * dx;
            }
            #pragma unroll
            for (int off = 16; off; off >>= 1)
                t += __shfl_xor(t, off, 64);
            sv += t;
        }
        // sv is half-wave-uniform; each of the 32 lanes in the half adds the
        // same value, corrected below by summing one representative per half.
        if (sv < SKIP_T && k != lab) acc += expf(-sv);
    }

    // acc is half-wave-uniform: acc(g) + acc(1-g) = wave total (each k once).
    acc += __shfl_xor(acc, 32, 64);

    __shared__ float wacc[4];
    if (lane == 0) wacc[wave] = acc;
    __syncthreads();
    if (tid == 0) partials[b] = wacc[0] + wacc[1] + wacc[2] + wacc[3];
}

__global__ __launch_bounds__(256) void reduce_kernel(
    const float* __restrict__ partials, float* __restrict__ out)
{
    float s = 0.0f;
    for (int i = threadIdx.x; i < B_SZ; i += 256) s += partials[i];
    #pragma unroll
    for (int off = 32; off; off >>= 1)
        s += __shfl_xor(s, off, 64);
    __shared__ float wacc[4];
    const int wave = threadIdx.x >> 6, lane = threadIdx.x & 63;
    if (lane == 0) wacc[wave] = s;
    __syncthreads();
    if (threadIdx.x == 0) out[0] = wacc[0] + wacc[1] + wacc[2] + wacc[3];
}

extern "C" void kernel_launch(void* const* d_in, const int* in_sizes, int n_in,
                              void* d_out, int out_size, void* d_ws, size_t ws_size,
                              hipStream_t stream) {
    const float* inputs  = (const float*)d_in[0];
    const float* decoded = (const float*)d_in[1];
    // d_in[3] is obj (==0 in setup) -> obj=False branch implemented.
    float* out      = (float*)d_out;
    float* partials = (float*)d_ws;   // B_SZ floats, fully overwritten each call

    // Reference declares labels int64; be dtype-robust via in_sizes.
    if (in_sizes[2] >= (int)(B_SZ * sizeof(long long))) {
        score_kernel<long long><<<B_SZ, 256, 0, stream>>>(
            inputs, decoded, (const long long*)d_in[2], partials);
    } else {
        score_kernel<int><<<B_SZ, 256, 0, stream>>>(
            inputs, decoded, (const int*)d_in[2], partials);
    }
    reduce_kernel<<<1, 256, 0, stream>>>(partials, out);
}